// Round 3
// baseline (662.983 us; speedup 1.0000x reference)
//
#include <hip/hip_runtime.h>
#include <hip/hip_bf16.h>
#include <cstdio>

// ---------------------------------------------------------------------------
// Attn_59940563583594: hidden[32,1024,768] -> QKV -> causal attn (no 1/sqrt(d))
//                      -> relu MLP(768->64) -> out[32,1024,2] fp32
// Numerics (verified R2: absmax 9.8e-4 vs 3.8e-3 threshold):
//   f16 storage/MFMA for hidden/W/q/k, no-max softmax (exp clamp 80,
//   unnormalized bf16 p, fp32 row sums, normalize in PV), bf16 PV + MLP.
// R3: global_load_lds(width=16) staging for all GEMMs; LDS chunks hold
//   16-row tiles with lane-order (row=i&15, colchunk=i>>4) so b128 frag
//   reads hit 8 distinct bank-quads / 16-lane phase (2-way = free, m136).
// ---------------------------------------------------------------------------

typedef _Float16 f16;
typedef f16    f16x8 __attribute__((ext_vector_type(8)));
typedef f16    f16x4 __attribute__((ext_vector_type(4)));
typedef __bf16 bfx8  __attribute__((ext_vector_type(8)));
typedef float  f32x4 __attribute__((ext_vector_type(4)));

#define MFMA_F16(a,b,c)  __builtin_amdgcn_mfma_f32_16x16x32_f16((a),(b),(c),0,0,0)
#define MFMA_BF16(a,b,c) __builtin_amdgcn_mfma_f32_16x16x32_bf16((a),(b),(c),0,0,0)

static constexpr int LDT = 136;  // v-transpose buffer stride

__device__ __forceinline__ void gl_lds16(const void* g, void* l) {
    __builtin_amdgcn_global_load_lds(
        (const __attribute__((address_space(1))) void*)g,
        (__attribute__((address_space(3))) void*)l, 16, 0, 0);
}

// ---------------- fp32 -> f16 convert ---------------------------------------
__global__ __launch_bounds__(256) void cvt_f32_f16(
    const float* __restrict__ x, f16* __restrict__ y, int n)
{
    int base = (blockIdx.x * 256 + threadIdx.x) * 4;
    if (base >= n) return;
    f32x4 v = *(const f32x4*)(x + base);
    f16x4 o;
    #pragma unroll
    for (int e = 0; e < 4; ++e) o[e] = (f16)v[e];
    *(f16x4*)(y + base) = o;
}

// ---------------- K1a: q,k projections (f16 NT GEMM, M=32768 N=768 K=768) ---
__global__ __launch_bounds__(256) void qk_kernel(
    const f16* __restrict__ h16, const f16* __restrict__ wq, const f16* __restrict__ wk,
    const float* __restrict__ bq, const float* __restrict__ bk,
    f16* __restrict__ q16, f16* __restrict__ k16)
{
    const int z = blockIdx.z;
    const f16* W = z ? wk : wq;
    const float* bias = z ? bk : bq;
    f16* out = z ? k16 : q16;

    __shared__ alignas(16) f16 As[128 * 32];
    __shared__ alignas(16) f16 Bs[128 * 32];

    const int t = threadIdx.x, lane = t & 63, wave = t >> 6;
    const int wm = (wave & 1) * 64, wn = (wave >> 1) * 64;
    const int quad = lane >> 4, l16 = lane & 15;
    const int m0 = blockIdx.y * 128, n0 = blockIdx.x * 128;
    const int c0 = wave * 2, c1 = c0 + 1;
    // staging: lane i -> (row = c*16 + (i&15), col chunk = (i>>4)*8)
    const f16* ga0 = &h16[(size_t)(m0 + c0 * 16 + l16) * 768 + quad * 8];
    const f16* ga1 = &h16[(size_t)(m0 + c1 * 16 + l16) * 768 + quad * 8];
    const f16* gb0 = &W[(size_t)(n0 + c0 * 16 + l16) * 768 + quad * 8];
    const f16* gb1 = &W[(size_t)(n0 + c1 * 16 + l16) * 768 + quad * 8];

    f32x4 acc[4][4] = {};
    for (int k0 = 0; k0 < 768; k0 += 32) {
        gl_lds16(ga0 + k0, &As[c0 * 512]);
        gl_lds16(ga1 + k0, &As[c1 * 512]);
        gl_lds16(gb0 + k0, &Bs[c0 * 512]);
        gl_lds16(gb1 + k0, &Bs[c1 * 512]);
        __syncthreads();
        f16x8 af[4], bg[4];
        #pragma unroll
        for (int i = 0; i < 4; ++i) {
            af[i] = *(const f16x8*)&As[(wm / 16 + i) * 512 + quad * 128 + l16 * 8];
            bg[i] = *(const f16x8*)&Bs[(wn / 16 + i) * 512 + quad * 128 + l16 * 8];
        }
        #pragma unroll
        for (int i = 0; i < 4; ++i)
            #pragma unroll
            for (int j = 0; j < 4; ++j)
                acc[i][j] = MFMA_F16(af[i], bg[j], acc[i][j]);
        __syncthreads();
    }
    #pragma unroll
    for (int j = 0; j < 4; ++j) {
        int col = n0 + wn + j * 16 + l16;
        float bb = bias[col];
        #pragma unroll
        for (int i = 0; i < 4; ++i)
            #pragma unroll
            for (int r = 0; r < 4; ++r) {
                int row = m0 + wm + i * 16 + quad * 4 + r;  // D: col=lane&15, row=quad*4+reg
                out[(size_t)row * 768 + col] = (f16)(acc[i][j][r] + bb);
            }
    }
}

// ---------------- K1b: v projection -> vT[b,e,s] bf16 (LDS transpose) -------
__global__ __launch_bounds__(256) void v_kernel(
    const f16* __restrict__ h16, const f16* __restrict__ wv, const float* __restrict__ bv,
    __bf16* __restrict__ vT)
{
    __shared__ alignas(16) f16 As[128 * 32];
    __shared__ alignas(16) f16 Bs[128 * 32];
    __shared__ alignas(16) __bf16 Tb[128 * LDT];

    const int t = threadIdx.x, lane = t & 63, wave = t >> 6;
    const int wm = (wave & 1) * 64, wn = (wave >> 1) * 64;
    const int quad = lane >> 4, l16 = lane & 15;
    const int m0 = blockIdx.y * 128, n0 = blockIdx.x * 128;
    const int c0 = wave * 2, c1 = c0 + 1;
    const f16* ga0 = &h16[(size_t)(m0 + c0 * 16 + l16) * 768 + quad * 8];
    const f16* ga1 = &h16[(size_t)(m0 + c1 * 16 + l16) * 768 + quad * 8];
    const f16* gb0 = &wv[(size_t)(n0 + c0 * 16 + l16) * 768 + quad * 8];
    const f16* gb1 = &wv[(size_t)(n0 + c1 * 16 + l16) * 768 + quad * 8];

    f32x4 acc[4][4] = {};
    for (int k0 = 0; k0 < 768; k0 += 32) {
        gl_lds16(ga0 + k0, &As[c0 * 512]);
        gl_lds16(ga1 + k0, &As[c1 * 512]);
        gl_lds16(gb0 + k0, &Bs[c0 * 512]);
        gl_lds16(gb1 + k0, &Bs[c1 * 512]);
        __syncthreads();
        f16x8 af[4], bg[4];
        #pragma unroll
        for (int i = 0; i < 4; ++i) {
            af[i] = *(const f16x8*)&As[(wm / 16 + i) * 512 + quad * 128 + l16 * 8];
            bg[i] = *(const f16x8*)&Bs[(wn / 16 + i) * 512 + quad * 128 + l16 * 8];
        }
        #pragma unroll
        for (int i = 0; i < 4; ++i)
            #pragma unroll
            for (int j = 0; j < 4; ++j)
                acc[i][j] = MFMA_F16(af[i], bg[j], acc[i][j]);
        __syncthreads();
    }
    // v^T tile via LDS: Tb[e_local][s_local]
    #pragma unroll
    for (int j = 0; j < 4; ++j) {
        int el = wn + j * 16 + l16;
        float bb = bv[n0 + el];
        #pragma unroll
        for (int i = 0; i < 4; ++i)
            #pragma unroll
            for (int r = 0; r < 4; ++r) {
                int sl = wm + i * 16 + quad * 4 + r;
                Tb[el * LDT + sl] = (__bf16)(acc[i][j][r] + bb);
            }
    }
    __syncthreads();
    const size_t bofs = (size_t)(m0 >> 10) * 768;
    const int s0 = m0 & 1023;
    const int ch = (t & 15) * 8;
    #pragma unroll
    for (int p = 0; p < 8; ++p) {
        int r = (t >> 4) + p * 16;
        bfx8 val = *(const bfx8*)&Tb[r * LDT + ch];
        *(bfx8*)&vT[(bofs + n0 + r) * 1024 + s0 + ch] = val;
    }
}

// ---------------- K2: p_u = exp(q@k^T + mask), bf16; fp32 rowsum partials ---
__global__ __launch_bounds__(256) void logits_kernel(
    const f16* __restrict__ q16, const f16* __restrict__ k16,
    const float* __restrict__ amask, __bf16* __restrict__ pu, float* __restrict__ psum)
{
    const int b = blockIdx.z, nt = blockIdx.x;
    const int m0 = blockIdx.y * 128, n0 = nt * 128;
    const int t = threadIdx.x;
    const size_t pb = (size_t)b << 20;

    if (n0 > m0) {  // fully masked tile: p = 0 exactly
        int r = t >> 1, half = t & 1;
        bfx8 zv;
        #pragma unroll
        for (int e = 0; e < 8; ++e) zv[e] = (__bf16)0.f;
        #pragma unroll
        for (int c = 0; c < 8; ++c)
            *(bfx8*)&pu[pb + (size_t)(m0 + r) * 1024 + n0 + half * 64 + c * 8] = zv;
        if (t < 128) psum[((size_t)b * 1024 + m0 + t) * 8 + nt] = 0.f;
        return;
    }

    __shared__ alignas(16) f16 As[128 * 32];
    __shared__ alignas(16) f16 Bs[128 * 32];
    __shared__ float rs[2][128];

    const int lane = t & 63, wave = t >> 6;
    const int wm = (wave & 1) * 64, wn = (wave >> 1) * 64;
    const int quad = lane >> 4, l16 = lane & 15;
    const size_t qb = (size_t)b * 1024 * 768;
    const int c0 = wave * 2, c1 = c0 + 1;
    const f16* ga0 = &q16[qb + (size_t)(m0 + c0 * 16 + l16) * 768 + quad * 8];
    const f16* ga1 = &q16[qb + (size_t)(m0 + c1 * 16 + l16) * 768 + quad * 8];
    const f16* gb0 = &k16[qb + (size_t)(n0 + c0 * 16 + l16) * 768 + quad * 8];
    const f16* gb1 = &k16[qb + (size_t)(n0 + c1 * 16 + l16) * 768 + quad * 8];

    f32x4 acc[4][4] = {};
    for (int k0 = 0; k0 < 768; k0 += 32) {
        gl_lds16(ga0 + k0, &As[c0 * 512]);
        gl_lds16(ga1 + k0, &As[c1 * 512]);
        gl_lds16(gb0 + k0, &Bs[c0 * 512]);
        gl_lds16(gb1 + k0, &Bs[c1 * 512]);
        __syncthreads();
        f16x8 af[4], bg[4];
        #pragma unroll
        for (int i = 0; i < 4; ++i) {
            af[i] = *(const f16x8*)&As[(wm / 16 + i) * 512 + quad * 128 + l16 * 8];
            bg[i] = *(const f16x8*)&Bs[(wn / 16 + i) * 512 + quad * 128 + l16 * 8];
        }
        #pragma unroll
        for (int i = 0; i < 4; ++i)
            #pragma unroll
            for (int j = 0; j < 4; ++j)
                acc[i][j] = MFMA_F16(af[i], bg[j], acc[i][j]);
        __syncthreads();
    }

    float rp[4][4] = {};
    #pragma unroll
    for (int j = 0; j < 4; ++j) {
        int col = n0 + wn + j * 16 + l16;
        float am = (1.0f - amask[b * 1024 + col]) * -10000.0f;
        #pragma unroll
        for (int i = 0; i < 4; ++i)
            #pragma unroll
            for (int r = 0; r < 4; ++r) {
                int row = m0 + wm + i * 16 + quad * 4 + r;
                float s = acc[i][j][r] + am;
                float pval = (col <= row) ? __expf(fminf(s, 80.0f)) : 0.0f;
                pu[pb + (size_t)row * 1024 + col] = (__bf16)pval;
                rp[i][r] += pval;
            }
    }
    #pragma unroll
    for (int i = 0; i < 4; ++i)
        #pragma unroll
        for (int r = 0; r < 4; ++r) {
            float v = rp[i][r];
            v += __shfl_xor(v, 1, 64);
            v += __shfl_xor(v, 2, 64);
            v += __shfl_xor(v, 4, 64);
            v += __shfl_xor(v, 8, 64);
            if (l16 == 0) rs[wn >> 6][wm + i * 16 + quad * 4 + r] = v;
        }
    __syncthreads();
    if (t < 128)
        psum[((size_t)b * 1024 + m0 + t) * 8 + nt] = rs[0][t] + rs[1][t];
}

// ---------------- K3: h = (p_u @ v) / rowsum, bf16 --------------------------
__global__ __launch_bounds__(256) void pv_kernel(
    const __bf16* __restrict__ pu, const __bf16* __restrict__ vT,
    const float* __restrict__ psum, __bf16* __restrict__ h)
{
    const int b = blockIdx.z;
    const int m0 = blockIdx.y * 128, n0 = blockIdx.x * 128;
    const int t = threadIdx.x, lane = t & 63, wave = t >> 6;
    const int wm = (wave & 1) * 64, wn = (wave >> 1) * 64;
    const int quad = lane >> 4, l16 = lane & 15;
    const size_t pb = (size_t)b << 20;
    const size_t vb = (size_t)b * 768 * 1024;

    __shared__ alignas(16) __bf16 As[128 * 32];
    __shared__ alignas(16) __bf16 Bs[128 * 32];
    __shared__ float invl[128];

    if (t < 128) {
        const float* pr = &psum[((size_t)b * 1024 + m0 + t) * 8];
        f32x4 a = *(const f32x4*)pr, c = *(const f32x4*)(pr + 4);
        invl[t] = 1.0f / (a[0] + a[1] + a[2] + a[3] + c[0] + c[1] + c[2] + c[3]);
    }

    const int c0 = wave * 2, c1 = c0 + 1;
    const __bf16* ga0 = &pu[pb + (size_t)(m0 + c0 * 16 + l16) * 1024 + quad * 8];
    const __bf16* ga1 = &pu[pb + (size_t)(m0 + c1 * 16 + l16) * 1024 + quad * 8];
    const __bf16* gb0 = &vT[vb + (size_t)(n0 + c0 * 16 + l16) * 1024 + quad * 8];
    const __bf16* gb1 = &vT[vb + (size_t)(n0 + c1 * 16 + l16) * 1024 + quad * 8];

    f32x4 acc[4][4] = {};
    const int kend = m0 + 128;  // p_u is exactly 0 above the diagonal
    for (int k0 = 0; k0 < kend; k0 += 32) {
        gl_lds16(ga0 + k0, &As[c0 * 512]);
        gl_lds16(ga1 + k0, &As[c1 * 512]);
        gl_lds16(gb0 + k0, &Bs[c0 * 512]);
        gl_lds16(gb1 + k0, &Bs[c1 * 512]);
        __syncthreads();
        bfx8 af[4], bg[4];
        #pragma unroll
        for (int i = 0; i < 4; ++i) {
            af[i] = *(const bfx8*)&As[(wm / 16 + i) * 512 + quad * 128 + l16 * 8];
            bg[i] = *(const bfx8*)&Bs[(wn / 16 + i) * 512 + quad * 128 + l16 * 8];
        }
        #pragma unroll
        for (int i = 0; i < 4; ++i)
            #pragma unroll
            for (int j = 0; j < 4; ++j)
                acc[i][j] = MFMA_BF16(af[i], bg[j], acc[i][j]);
        __syncthreads();
    }
    #pragma unroll
    for (int j = 0; j < 4; ++j) {
        int col = n0 + wn + j * 16 + l16;
        #pragma unroll
        for (int i = 0; i < 4; ++i)
            #pragma unroll
            for (int r = 0; r < 4; ++r) {
                int rl = wm + i * 16 + quad * 4 + r;
                h[((size_t)b * 1024 + m0 + rl) * 768 + col] = (__bf16)(acc[i][j][r] * invl[rl]);
            }
    }
}

// ---------------- K4: out = relu(h @ W1^T + b1) @ W2^T + b2 -----------------
__global__ __launch_bounds__(256) void mlp_kernel(
    const __bf16* __restrict__ h, const float* __restrict__ W1, const float* __restrict__ b1,
    const float* __restrict__ W2, const float* __restrict__ b2, float* __restrict__ out)
{
    const int wave = threadIdx.x >> 6, lane = threadIdx.x & 63;
    const int quad = lane >> 4, l16 = lane & 15;
    const int m0 = blockIdx.x * 64 + wave * 16;

    f32x4 acc[4] = {};
    for (int k0 = 0; k0 < 768; k0 += 32) {
        bfx8 af = *(const bfx8*)&h[(size_t)(m0 + l16) * 768 + k0 + quad * 8];
        #pragma unroll
        for (int j = 0; j < 4; ++j) {
            const float* wp = W1 + (size_t)(j * 16 + l16) * 768 + k0 + quad * 8;
            f32x4 w0 = *(const f32x4*)wp;
            f32x4 w1 = *(const f32x4*)(wp + 4);
            bfx8 bg;
            #pragma unroll
            for (int e = 0; e < 4; ++e) { bg[e] = (__bf16)w0[e]; bg[e + 4] = (__bf16)w1[e]; }
            acc[j] = MFMA_BF16(af, bg, acc[j]);
        }
    }
    float part[4][2] = {};
    #pragma unroll
    for (int j = 0; j < 4; ++j) {
        int c = j * 16 + l16;
        float bb = b1[c];
        float w20 = W2[c], w21 = W2[64 + c];
        #pragma unroll
        for (int r = 0; r < 4; ++r) {
            float x = fmaxf(acc[j][r] + bb, 0.f);
            part[r][0] += x * w20;
            part[r][1] += x * w21;
        }
    }
    #pragma unroll
    for (int off = 1; off < 16; off <<= 1)
        #pragma unroll
        for (int r = 0; r < 4; ++r) {
            part[r][0] += __shfl_xor(part[r][0], off, 64);
            part[r][1] += __shfl_xor(part[r][1], off, 64);
        }
    if (l16 == 0) {
        #pragma unroll
        for (int r = 0; r < 4; ++r) {
            int row = m0 + quad * 4 + r;
            out[(size_t)row * 2 + 0] = part[r][0] + b2[0];
            out[(size_t)row * 2 + 1] = part[r][1] + b2[1];
        }
    }
}

// ---------------------------------------------------------------------------
extern "C" void kernel_launch(void* const* d_in, const int* in_sizes, int n_in,
                              void* d_out, int out_size, void* d_ws, size_t ws_size,
                              hipStream_t stream)
{
    const float* hidden = (const float*)d_in[0];
    const float* amask  = (const float*)d_in[1];
    const float* Wk = (const float*)d_in[2];
    const float* bk = (const float*)d_in[3];
    const float* Wq = (const float*)d_in[4];
    const float* bq = (const float*)d_in[5];
    const float* Wv = (const float*)d_in[6];
    const float* bv = (const float*)d_in[7];
    const float* W1 = (const float*)d_in[8];
    const float* b1 = (const float*)d_in[9];
    const float* W2 = (const float*)d_in[10];
    const float* b2 = (const float*)d_in[11];
    float* out = (float*)d_out;

    char* ws = (char*)d_ws;
    const size_t MB = 1024 * 1024;
    // Phase 1 (qkv): h16 @0 (48MB), w16 @48MB (3.4MB)  [dead after qkv]
    // Phase 2 (logits): pu @0 (64MB, aliases phase1), psum @64MB (1MB)
    // q16 @66MB (48), k16 @114MB (48), vT @162MB (48)
    // Phase 3 (pv/mlp): h @66MB (aliases q16, dead after logits)
    f16* h16 = (f16*)ws;
    f16* wq16 = (f16*)(ws + 48 * MB);
    f16* wk16 = wq16 + 589824;
    f16* wv16 = wk16 + 589824;
    __bf16* pu  = (__bf16*)ws;
    float*  psum = (float*)(ws + 64 * MB);
    f16* q16 = (f16*)(ws + 66 * MB);
    f16* k16 = (f16*)(ws + 114 * MB);
    __bf16* vT = (__bf16*)(ws + 162 * MB);
    __bf16* h  = (__bf16*)(ws + 66 * MB);
    const size_t NEED = 210 * MB;
    if (ws_size < NEED) {
        fprintf(stderr, "[Attn kernel] ws too small: %zu < %zu — skipping launches\n",
                ws_size, NEED);
        return;
    }

    cvt_f32_f16<<<24576, 256, 0, stream>>>(hidden, h16, 25165824);
    cvt_f32_f16<<<576, 256, 0, stream>>>(Wq, wq16, 589824);
    cvt_f32_f16<<<576, 256, 0, stream>>>(Wk, wk16, 589824);
    cvt_f32_f16<<<576, 256, 0, stream>>>(Wv, wv16, 589824);

    qk_kernel<<<dim3(6, 256, 2), 256, 0, stream>>>(h16, wq16, wk16, bq, bk, q16, k16);
    v_kernel<<<dim3(6, 256), 256, 0, stream>>>(h16, wv16, bv, vT);
    logits_kernel<<<dim3(8, 8, 32), 256, 0, stream>>>(q16, k16, amask, pu, psum);
    pv_kernel<<<dim3(6, 8, 32), 256, 0, stream>>>(pu, vT, psum, h);
    mlp_kernel<<<512, 256, 0, stream>>>(h, W1, b1, W2, b2, out);
}

// Round 4
// 662.898 us; speedup vs baseline: 1.0001x; 1.0001x over previous
//
#include <hip/hip_runtime.h>
#include <hip/hip_bf16.h>
#include <cstdio>

// ---------------------------------------------------------------------------
// Attn_59940563583594: hidden[32,1024,768] -> QKV -> causal attn (no 1/sqrt(d))
//                      -> relu MLP(768->64) -> out[32,1024,2] fp32
// Numerics (verified R2/R3: absmax 9.8e-4 vs 3.8e-3 threshold):
//   f16 storage/MFMA for hidden/W/q/k, no-max softmax (exp clamp 80,
//   unnormalized bf16 p, fp32 row sums, normalize in PV), bf16 PV + MLP.
// R4: single-barrier double-buffered global_load_lds K-loop. R3 showed the
//   2-barrier loop stalls ~3460 cyc/step on the vmcnt(0) drain at the
//   barrier right after issuing the loads. Now: barrier publishes buf A,
//   we immediately issue k+1 into buf B, then compute A — the next
//   barrier's drain targets loads that flew during the compute phase.
// ---------------------------------------------------------------------------

typedef _Float16 f16;
typedef f16    f16x8 __attribute__((ext_vector_type(8)));
typedef f16    f16x4 __attribute__((ext_vector_type(4)));
typedef __bf16 bfx8  __attribute__((ext_vector_type(8)));
typedef float  f32x4 __attribute__((ext_vector_type(4)));

#define MFMA_F16(a,b,c)  __builtin_amdgcn_mfma_f32_16x16x32_f16((a),(b),(c),0,0,0)
#define MFMA_BF16(a,b,c) __builtin_amdgcn_mfma_f32_16x16x32_bf16((a),(b),(c),0,0,0)

static constexpr int LDT = 136;  // v-transpose buffer stride

__device__ __forceinline__ void gl_lds16(const void* g, void* l) {
    __builtin_amdgcn_global_load_lds(
        (const __attribute__((address_space(1))) void*)g,
        (__attribute__((address_space(3))) void*)l, 16, 0, 0);
}

// ---------------- fp32 -> f16 converts --------------------------------------
__global__ __launch_bounds__(256) void cvt_f32_f16(
    const float* __restrict__ x, f16* __restrict__ y, int n)
{
    int base = (blockIdx.x * 256 + threadIdx.x) * 4;
    if (base >= n) return;
    f32x4 v = *(const f32x4*)(x + base);
    f16x4 o;
    #pragma unroll
    for (int e = 0; e < 4; ++e) o[e] = (f16)v[e];
    *(f16x4*)(y + base) = o;
}

__global__ __launch_bounds__(256) void cvt3_w(
    const float* __restrict__ Wq, const float* __restrict__ Wk, const float* __restrict__ Wv,
    f16* __restrict__ oq, f16* __restrict__ ok, f16* __restrict__ ov)
{
    const int z = blockIdx.y;
    const float* s = (z == 0) ? Wq : (z == 1) ? Wk : Wv;
    f16* d = (z == 0) ? oq : (z == 1) ? ok : ov;
    int base = (blockIdx.x * 256 + threadIdx.x) * 4;
    f32x4 v = *(const f32x4*)(s + base);
    f16x4 o;
    #pragma unroll
    for (int e = 0; e < 4; ++e) o[e] = (f16)v[e];
    *(f16x4*)(d + base) = o;
}

// ---------------- K1a: q,k projections (f16 NT GEMM, M=32768 N=768 K=768) ---
__global__ __launch_bounds__(256) void qk_kernel(
    const f16* __restrict__ h16, const f16* __restrict__ wq, const f16* __restrict__ wk,
    const float* __restrict__ bq, const float* __restrict__ bk,
    f16* __restrict__ q16, f16* __restrict__ k16)
{
    const int z = blockIdx.z;
    const f16* W = z ? wk : wq;
    const float* bias = z ? bk : bq;
    f16* out = z ? k16 : q16;

    __shared__ alignas(16) char smem[32768];
    f16 (*As)[4096] = (f16(*)[4096])smem;            // [2][128*32]
    f16 (*Bs)[4096] = (f16(*)[4096])(smem + 16384);  // [2][128*32]

    const int t = threadIdx.x, lane = t & 63, wave = t >> 6;
    const int wm = (wave & 1) * 64, wn = (wave >> 1) * 64;
    const int quad = lane >> 4, l16 = lane & 15;
    const int m0 = blockIdx.y * 128, n0 = blockIdx.x * 128;
    const int c0 = wave * 2, c1 = c0 + 1;
    // staging: lane i -> (row = c*16 + (i&15), col chunk = (i>>4)*8)
    const f16* ga0 = &h16[(size_t)(m0 + c0 * 16 + l16) * 768 + quad * 8];
    const f16* ga1 = &h16[(size_t)(m0 + c1 * 16 + l16) * 768 + quad * 8];
    const f16* gb0 = &W[(size_t)(n0 + c0 * 16 + l16) * 768 + quad * 8];
    const f16* gb1 = &W[(size_t)(n0 + c1 * 16 + l16) * 768 + quad * 8];

    f32x4 acc[4][4] = {};
    auto stage = [&](int k0, int buf) {
        gl_lds16(ga0 + k0, &As[buf][c0 * 512]);
        gl_lds16(ga1 + k0, &As[buf][c1 * 512]);
        gl_lds16(gb0 + k0, &Bs[buf][c0 * 512]);
        gl_lds16(gb1 + k0, &Bs[buf][c1 * 512]);
    };
    auto compute = [&](int buf) {
        f16x8 af[4], bg[4];
        #pragma unroll
        for (int i = 0; i < 4; ++i) {
            af[i] = *(const f16x8*)&As[buf][(wm / 16 + i) * 512 + quad * 128 + l16 * 8];
            bg[i] = *(const f16x8*)&Bs[buf][(wn / 16 + i) * 512 + quad * 128 + l16 * 8];
        }
        #pragma unroll
        for (int i = 0; i < 4; ++i)
            #pragma unroll
            for (int j = 0; j < 4; ++j)
                acc[i][j] = MFMA_F16(af[i], bg[j], acc[i][j]);
    };

    stage(0, 0);
    int cur = 0;
    for (int k0 = 32; k0 < 768; k0 += 32) {
        __syncthreads();          // drains this wave's prior loads: buf[cur] ready
        stage(k0, cur ^ 1);       // async into other buffer, flies during compute
        compute(cur);
        cur ^= 1;
    }
    __syncthreads();
    compute(cur);

    #pragma unroll
    for (int j = 0; j < 4; ++j) {
        int col = n0 + wn + j * 16 + l16;
        float bb = bias[col];
        #pragma unroll
        for (int i = 0; i < 4; ++i)
            #pragma unroll
            for (int r = 0; r < 4; ++r) {
                int row = m0 + wm + i * 16 + quad * 4 + r;  // D: col=lane&15, row=quad*4+reg
                out[(size_t)row * 768 + col] = (f16)(acc[i][j][r] + bb);
            }
    }
}

// ---------------- K1b: v projection -> vT[b,e,s] bf16 (LDS transpose) -------
__global__ __launch_bounds__(256) void v_kernel(
    const f16* __restrict__ h16, const f16* __restrict__ wv, const float* __restrict__ bv,
    __bf16* __restrict__ vT)
{
    __shared__ alignas(16) char smem[34816];         // max(32KB dbuf, 34KB Tb)
    f16 (*As)[4096] = (f16(*)[4096])smem;
    f16 (*Bs)[4096] = (f16(*)[4096])(smem + 16384);
    __bf16* Tb = (__bf16*)smem;                      // reused after K-loop

    const int t = threadIdx.x, lane = t & 63, wave = t >> 6;
    const int wm = (wave & 1) * 64, wn = (wave >> 1) * 64;
    const int quad = lane >> 4, l16 = lane & 15;
    const int m0 = blockIdx.y * 128, n0 = blockIdx.x * 128;
    const int c0 = wave * 2, c1 = c0 + 1;
    const f16* ga0 = &h16[(size_t)(m0 + c0 * 16 + l16) * 768 + quad * 8];
    const f16* ga1 = &h16[(size_t)(m0 + c1 * 16 + l16) * 768 + quad * 8];
    const f16* gb0 = &wv[(size_t)(n0 + c0 * 16 + l16) * 768 + quad * 8];
    const f16* gb1 = &wv[(size_t)(n0 + c1 * 16 + l16) * 768 + quad * 8];

    f32x4 acc[4][4] = {};
    auto stage = [&](int k0, int buf) {
        gl_lds16(ga0 + k0, &As[buf][c0 * 512]);
        gl_lds16(ga1 + k0, &As[buf][c1 * 512]);
        gl_lds16(gb0 + k0, &Bs[buf][c0 * 512]);
        gl_lds16(gb1 + k0, &Bs[buf][c1 * 512]);
    };
    auto compute = [&](int buf) {
        f16x8 af[4], bg[4];
        #pragma unroll
        for (int i = 0; i < 4; ++i) {
            af[i] = *(const f16x8*)&As[buf][(wm / 16 + i) * 512 + quad * 128 + l16 * 8];
            bg[i] = *(const f16x8*)&Bs[buf][(wn / 16 + i) * 512 + quad * 128 + l16 * 8];
        }
        #pragma unroll
        for (int i = 0; i < 4; ++i)
            #pragma unroll
            for (int j = 0; j < 4; ++j)
                acc[i][j] = MFMA_F16(af[i], bg[j], acc[i][j]);
    };

    stage(0, 0);
    int cur = 0;
    for (int k0 = 32; k0 < 768; k0 += 32) {
        __syncthreads();
        stage(k0, cur ^ 1);
        compute(cur);
        cur ^= 1;
    }
    __syncthreads();
    compute(cur);
    __syncthreads();   // before Tb overwrites the staging buffers

    // v^T tile via LDS: Tb[e_local][s_local]
    #pragma unroll
    for (int j = 0; j < 4; ++j) {
        int el = wn + j * 16 + l16;
        float bb = bv[n0 + el];
        #pragma unroll
        for (int i = 0; i < 4; ++i)
            #pragma unroll
            for (int r = 0; r < 4; ++r) {
                int sl = wm + i * 16 + quad * 4 + r;
                Tb[el * LDT + sl] = (__bf16)(acc[i][j][r] + bb);
            }
    }
    __syncthreads();
    const size_t bofs = (size_t)(m0 >> 10) * 768;
    const int s0 = m0 & 1023;
    const int ch = (t & 15) * 8;
    #pragma unroll
    for (int p = 0; p < 8; ++p) {
        int r = (t >> 4) + p * 16;
        bfx8 val = *(const bfx8*)&Tb[r * LDT + ch];
        *(bfx8*)&vT[(bofs + n0 + r) * 1024 + s0 + ch] = val;
    }
}

// ---------------- K2: p_u = exp(q@k^T + mask), bf16; fp32 rowsum partials ---
__global__ __launch_bounds__(256) void logits_kernel(
    const f16* __restrict__ q16, const f16* __restrict__ k16,
    const float* __restrict__ amask, __bf16* __restrict__ pu, float* __restrict__ psum)
{
    const int b = blockIdx.z, nt = blockIdx.x;
    const int m0 = blockIdx.y * 128, n0 = nt * 128;
    const int t = threadIdx.x;
    const size_t pb = (size_t)b << 20;

    if (n0 > m0) {  // fully masked tile: p = 0 exactly
        int r = t >> 1, half = t & 1;
        bfx8 zv;
        #pragma unroll
        for (int e = 0; e < 8; ++e) zv[e] = (__bf16)0.f;
        #pragma unroll
        for (int c = 0; c < 8; ++c)
            *(bfx8*)&pu[pb + (size_t)(m0 + r) * 1024 + n0 + half * 64 + c * 8] = zv;
        if (t < 128) psum[((size_t)b * 1024 + m0 + t) * 8 + nt] = 0.f;
        return;
    }

    __shared__ alignas(16) char smem[32768];
    f16 (*As)[4096] = (f16(*)[4096])smem;
    f16 (*Bs)[4096] = (f16(*)[4096])(smem + 16384);
    __shared__ float rs[2][128];

    const int lane = t & 63, wave = t >> 6;
    const int wm = (wave & 1) * 64, wn = (wave >> 1) * 64;
    const int quad = lane >> 4, l16 = lane & 15;
    const size_t qb = (size_t)b * 1024 * 768;
    const int c0 = wave * 2, c1 = c0 + 1;
    const f16* ga0 = &q16[qb + (size_t)(m0 + c0 * 16 + l16) * 768 + quad * 8];
    const f16* ga1 = &q16[qb + (size_t)(m0 + c1 * 16 + l16) * 768 + quad * 8];
    const f16* gb0 = &k16[qb + (size_t)(n0 + c0 * 16 + l16) * 768 + quad * 8];
    const f16* gb1 = &k16[qb + (size_t)(n0 + c1 * 16 + l16) * 768 + quad * 8];

    f32x4 acc[4][4] = {};
    auto stage = [&](int k0, int buf) {
        gl_lds16(ga0 + k0, &As[buf][c0 * 512]);
        gl_lds16(ga1 + k0, &As[buf][c1 * 512]);
        gl_lds16(gb0 + k0, &Bs[buf][c0 * 512]);
        gl_lds16(gb1 + k0, &Bs[buf][c1 * 512]);
    };
    auto compute = [&](int buf) {
        f16x8 af[4], bg[4];
        #pragma unroll
        for (int i = 0; i < 4; ++i) {
            af[i] = *(const f16x8*)&As[buf][(wm / 16 + i) * 512 + quad * 128 + l16 * 8];
            bg[i] = *(const f16x8*)&Bs[buf][(wn / 16 + i) * 512 + quad * 128 + l16 * 8];
        }
        #pragma unroll
        for (int i = 0; i < 4; ++i)
            #pragma unroll
            for (int j = 0; j < 4; ++j)
                acc[i][j] = MFMA_F16(af[i], bg[j], acc[i][j]);
    };

    stage(0, 0);
    int cur = 0;
    for (int k0 = 32; k0 < 768; k0 += 32) {
        __syncthreads();
        stage(k0, cur ^ 1);
        compute(cur);
        cur ^= 1;
    }
    __syncthreads();
    compute(cur);

    float rp[4][4] = {};
    #pragma unroll
    for (int j = 0; j < 4; ++j) {
        int col = n0 + wn + j * 16 + l16;
        float am = (1.0f - amask[b * 1024 + col]) * -10000.0f;
        #pragma unroll
        for (int i = 0; i < 4; ++i)
            #pragma unroll
            for (int r = 0; r < 4; ++r) {
                int row = m0 + wm + i * 16 + quad * 4 + r;
                float s = acc[i][j][r] + am;
                float pval = (col <= row) ? __expf(fminf(s, 80.0f)) : 0.0f;
                pu[pb + (size_t)row * 1024 + col] = (__bf16)pval;
                rp[i][r] += pval;
            }
    }
    #pragma unroll
    for (int i = 0; i < 4; ++i)
        #pragma unroll
        for (int r = 0; r < 4; ++r) {
            float v = rp[i][r];
            v += __shfl_xor(v, 1, 64);
            v += __shfl_xor(v, 2, 64);
            v += __shfl_xor(v, 4, 64);
            v += __shfl_xor(v, 8, 64);
            if (l16 == 0) rs[wn >> 6][wm + i * 16 + quad * 4 + r] = v;
        }
    __syncthreads();
    if (t < 128)
        psum[((size_t)b * 1024 + m0 + t) * 8 + nt] = rs[0][t] + rs[1][t];
}

// ---------------- K3: h = (p_u @ v) / rowsum, bf16 --------------------------
__global__ __launch_bounds__(256) void pv_kernel(
    const __bf16* __restrict__ pu, const __bf16* __restrict__ vT,
    const float* __restrict__ psum, __bf16* __restrict__ h)
{
    const int b = blockIdx.z;
    const int m0 = blockIdx.y * 128, n0 = blockIdx.x * 128;
    const int t = threadIdx.x, lane = t & 63, wave = t >> 6;
    const int wm = (wave & 1) * 64, wn = (wave >> 1) * 64;
    const int quad = lane >> 4, l16 = lane & 15;
    const size_t pb = (size_t)b << 20;
    const size_t vb = (size_t)b * 768 * 1024;

    __shared__ alignas(16) char smem[32768];
    __bf16 (*As)[4096] = (__bf16(*)[4096])smem;
    __bf16 (*Bs)[4096] = (__bf16(*)[4096])(smem + 16384);
    __shared__ float invl[128];

    if (t < 128) {
        const float* pr = &psum[((size_t)b * 1024 + m0 + t) * 8];
        f32x4 a = *(const f32x4*)pr, c = *(const f32x4*)(pr + 4);
        invl[t] = 1.0f / (a[0] + a[1] + a[2] + a[3] + c[0] + c[1] + c[2] + c[3]);
    }

    const int c0 = wave * 2, c1 = c0 + 1;
    const __bf16* ga0 = &pu[pb + (size_t)(m0 + c0 * 16 + l16) * 1024 + quad * 8];
    const __bf16* ga1 = &pu[pb + (size_t)(m0 + c1 * 16 + l16) * 1024 + quad * 8];
    const __bf16* gb0 = &vT[vb + (size_t)(n0 + c0 * 16 + l16) * 1024 + quad * 8];
    const __bf16* gb1 = &vT[vb + (size_t)(n0 + c1 * 16 + l16) * 1024 + quad * 8];

    f32x4 acc[4][4] = {};
    auto stage = [&](int k0, int buf) {
        gl_lds16(ga0 + k0, &As[buf][c0 * 512]);
        gl_lds16(ga1 + k0, &As[buf][c1 * 512]);
        gl_lds16(gb0 + k0, &Bs[buf][c0 * 512]);
        gl_lds16(gb1 + k0, &Bs[buf][c1 * 512]);
    };
    auto compute = [&](int buf) {
        bfx8 af[4], bg[4];
        #pragma unroll
        for (int i = 0; i < 4; ++i) {
            af[i] = *(const bfx8*)&As[buf][(wm / 16 + i) * 512 + quad * 128 + l16 * 8];
            bg[i] = *(const bfx8*)&Bs[buf][(wn / 16 + i) * 512 + quad * 128 + l16 * 8];
        }
        #pragma unroll
        for (int i = 0; i < 4; ++i)
            #pragma unroll
            for (int j = 0; j < 4; ++j)
                acc[i][j] = MFMA_BF16(af[i], bg[j], acc[i][j]);
    };

    const int kend = m0 + 128;  // p_u is exactly 0 above the diagonal
    stage(0, 0);
    int cur = 0;
    for (int k0 = 32; k0 < kend; k0 += 32) {
        __syncthreads();
        stage(k0, cur ^ 1);
        compute(cur);
        cur ^= 1;
    }
    __syncthreads();
    compute(cur);

    #pragma unroll
    for (int j = 0; j < 4; ++j) {
        int col = n0 + wn + j * 16 + l16;
        #pragma unroll
        for (int i = 0; i < 4; ++i)
            #pragma unroll
            for (int r = 0; r < 4; ++r) {
                int rl = wm + i * 16 + quad * 4 + r;
                h[((size_t)b * 1024 + m0 + rl) * 768 + col] = (__bf16)(acc[i][j][r] * invl[rl]);
            }
    }
}

// ---------------- K4: out = relu(h @ W1^T + b1) @ W2^T + b2 -----------------
__global__ __launch_bounds__(256) void mlp_kernel(
    const __bf16* __restrict__ h, const float* __restrict__ W1, const float* __restrict__ b1,
    const float* __restrict__ W2, const float* __restrict__ b2, float* __restrict__ out)
{
    const int wave = threadIdx.x >> 6, lane = threadIdx.x & 63;
    const int quad = lane >> 4, l16 = lane & 15;
    const int m0 = blockIdx.x * 64 + wave * 16;

    f32x4 acc[4] = {};
    for (int k0 = 0; k0 < 768; k0 += 32) {
        bfx8 af = *(const bfx8*)&h[(size_t)(m0 + l16) * 768 + k0 + quad * 8];
        #pragma unroll
        for (int j = 0; j < 4; ++j) {
            const float* wp = W1 + (size_t)(j * 16 + l16) * 768 + k0 + quad * 8;
            f32x4 w0 = *(const f32x4*)wp;
            f32x4 w1 = *(const f32x4*)(wp + 4);
            bfx8 bg;
            #pragma unroll
            for (int e = 0; e < 4; ++e) { bg[e] = (__bf16)w0[e]; bg[e + 4] = (__bf16)w1[e]; }
            acc[j] = MFMA_BF16(af, bg, acc[j]);
        }
    }
    float part[4][2] = {};
    #pragma unroll
    for (int j = 0; j < 4; ++j) {
        int c = j * 16 + l16;
        float bb = b1[c];
        float w20 = W2[c], w21 = W2[64 + c];
        #pragma unroll
        for (int r = 0; r < 4; ++r) {
            float x = fmaxf(acc[j][r] + bb, 0.f);
            part[r][0] += x * w20;
            part[r][1] += x * w21;
        }
    }
    #pragma unroll
    for (int off = 1; off < 16; off <<= 1)
        #pragma unroll
        for (int r = 0; r < 4; ++r) {
            part[r][0] += __shfl_xor(part[r][0], off, 64);
            part[r][1] += __shfl_xor(part[r][1], off, 64);
        }
    if (l16 == 0) {
        #pragma unroll
        for (int r = 0; r < 4; ++r) {
            int row = m0 + quad * 4 + r;
            out[(size_t)row * 2 + 0] = part[r][0] + b2[0];
            out[(size_t)row * 2 + 1] = part[r][1] + b2[1];
        }
    }
}

// ---------------------------------------------------------------------------
extern "C" void kernel_launch(void* const* d_in, const int* in_sizes, int n_in,
                              void* d_out, int out_size, void* d_ws, size_t ws_size,
                              hipStream_t stream)
{
    const float* hidden = (const float*)d_in[0];
    const float* amask  = (const float*)d_in[1];
    const float* Wk = (const float*)d_in[2];
    const float* bk = (const float*)d_in[3];
    const float* Wq = (const float*)d_in[4];
    const float* bq = (const float*)d_in[5];
    const float* Wv = (const float*)d_in[6];
    const float* bv = (const float*)d_in[7];
    const float* W1 = (const float*)d_in[8];
    const float* b1 = (const float*)d_in[9];
    const float* W2 = (const float*)d_in[10];
    const float* b2 = (const float*)d_in[11];
    float* out = (float*)d_out;

    char* ws = (char*)d_ws;
    const size_t MB = 1024 * 1024;
    // Phase 1 (qkv): h16 @0 (48MB), w16 @48MB (3.4MB)  [dead after qkv]
    // Phase 2 (logits): pu @0 (64MB, aliases phase1), psum @64MB (1MB)
    // q16 @66MB (48), k16 @114MB (48), vT @162MB (48)
    // Phase 3 (pv/mlp): h @66MB (aliases q16, dead after logits)
    f16* h16 = (f16*)ws;
    f16* wq16 = (f16*)(ws + 48 * MB);
    f16* wk16 = wq16 + 589824;
    f16* wv16 = wk16 + 589824;
    __bf16* pu  = (__bf16*)ws;
    float*  psum = (float*)(ws + 64 * MB);
    f16* q16 = (f16*)(ws + 66 * MB);
    f16* k16 = (f16*)(ws + 114 * MB);
    __bf16* vT = (__bf16*)(ws + 162 * MB);
    __bf16* h  = (__bf16*)(ws + 66 * MB);
    const size_t NEED = 210 * MB;
    if (ws_size < NEED) {
        fprintf(stderr, "[Attn kernel] ws too small: %zu < %zu — skipping launches\n",
                ws_size, NEED);
        return;
    }

    cvt_f32_f16<<<24576, 256, 0, stream>>>(hidden, h16, 25165824);
    cvt3_w<<<dim3(576, 3), 256, 0, stream>>>(Wq, Wk, Wv, wq16, wk16, wv16);

    qk_kernel<<<dim3(6, 256, 2), 256, 0, stream>>>(h16, wq16, wk16, bq, bk, q16, k16);
    v_kernel<<<dim3(6, 256), 256, 0, stream>>>(h16, wv16, bv, vT);
    logits_kernel<<<dim3(8, 8, 32), 256, 0, stream>>>(q16, k16, amask, pu, psum);
    pv_kernel<<<dim3(6, 8, 32), 256, 0, stream>>>(pu, vT, psum, h);
    mlp_kernel<<<512, 256, 0, stream>>>(h, W1, b1, W2, b2, out);
}